// Round 2
// baseline (946.106 us; speedup 1.0000x reference)
//
#include <hip/hip_runtime.h>

#define B_SZ 128
#define NPTS 2048
#define CATE 55

// prep: per-batch argmax of cls_score -> cid; zero the row-sum scratch.
__global__ __launch_bounds__(256) void prep_kernel(
    const float* __restrict__ cls, int* __restrict__ cid,
    float* __restrict__ sums, int nsums)
{
    int gt = blockIdx.x * 256 + threadIdx.x;
    if (gt < B_SZ) {
        const float* p = cls + gt * CATE;
        float best = p[0]; int bi = 0;
        #pragma unroll
        for (int i = 1; i < CATE; ++i) {
            float v = p[i];
            if (v > best) { best = v; bi = i; }   // strict > => first max, matches argmax
        }
        cid[gt] = bi;
    }
    for (int i = gt; i < nsums; i += gridDim.x * 256) sums[i] = 0.0f;
}

// Block = (batch b, 64-column chunk). 256 threads = 64 cols x 4 row-groups
// (row-group == wave id, so W/bias indices are wave-uniform -> s_load).
// Feat tile [K x 64] staged in LDS.
//
// Round-3 restructure (round-4 = retry after infra failure): register-tile
// the x column. Old code did 1 ds_read per 8 FMAs interleaved with scalar W
// s_loads; ds_read and s_load share lgkmcnt and complete OOO w.r.t. each
// other, forcing conservative lgkmcnt(0) drains every ~4 j's -> VALUBusy
// 28.6%, dur 309us vs ~60us VALU roofline.
// Now: batch 32 ds_reads into xr[32] VGPRs, then a pure-FMA region of
// 8 rows x 32 j = 256 FMAs (W via hoisted s_loads). One drain per 256 FMAs.
template<int K>
__global__ __launch_bounds__(256) void expert_exp_kernel(
    const float* __restrict__ feat,   // [B,K,NPTS]
    const float* __restrict__ W,      // [CATE,K,K]
    const float* __restrict__ bias,   // [CATE,K]
    const int*   __restrict__ cid,    // [B]
    float*       __restrict__ out,    // [B,K,NPTS] (exp values)
    float*       __restrict__ sums)   // [B*K]
{
    constexpr int RT = K / 4;                       // rows per thread
    constexpr int JT = 32;                          // j-tile held in VGPRs
    const int b     = blockIdx.x >> 5;              // 2048/64 = 32 chunks
    const int chunk = blockIdx.x & 31;
    const int col   = threadIdx.x & 63;             // lane == column
    const int rg    = __builtin_amdgcn_readfirstlane(threadIdx.x >> 6); // wave id, SGPR
    const int c     = __builtin_amdgcn_readfirstlane(cid[b]);

    const float* Wc = W + (size_t)c * K * K;
    const float* bc = bias + (size_t)c * K;
    const float* fb = feat + (size_t)b * K * NPTS + chunk * 64;
    float*       ob = out  + (size_t)b * K * NPTS + chunk * 64 + col;

    __shared__ float xs[K * 64];                    // K=128 -> 32 KB (5 blocks/CU)

    // Stage feat tile: float4, 16 rows per 256-thread pass, coalesced.
    {
        const int r0 = threadIdx.x >> 4;            // 0..15
        const int c4 = (threadIdx.x & 15) << 2;     // 0,4,..,60
        #pragma unroll
        for (int p = 0; p < K / 16; ++p) {
            const int r = p * 16 + r0;
            const float4 v = *(const float4*)(fb + (size_t)r * NPTS + c4);
            *(float4*)(&xs[r * 64 + c4]) = v;
        }
    }
    __syncthreads();

    const int i0 = rg * RT;
    #pragma unroll 1
    for (int ic = 0; ic < RT; ic += 8) {
        float acc[8];
        #pragma unroll
        for (int t = 0; t < 8; ++t) acc[t] = bc[i0 + ic + t];

        #pragma unroll 1
        for (int jt = 0; jt < K; jt += JT) {
            // Batch-load the j-tile of this thread's column into registers.
            // 32 back-to-back ds_read_b32 (stride-1 across lanes: 2-way = free).
            float xr[JT];
            #pragma unroll
            for (int u = 0; u < JT; ++u) xr[u] = xs[(jt + u) * 64 + col];

            // Pure-FMA region: 256 FMAs, no LDS ops. All indices compile-time
            // -> xr stays in VGPRs; W addresses wave-uniform -> s_load_dwordx8.
            #pragma unroll
            for (int t = 0; t < 8; ++t) {
                #pragma unroll
                for (int u = 0; u < JT; ++u)
                    acc[t] = fmaf(Wc[(size_t)(i0 + ic + t) * K + jt + u], xr[u], acc[t]);
            }
        }

        #pragma unroll
        for (int t = 0; t < 8; ++t) {
            const int i = i0 + ic + t;
            const float x = xs[i * 64 + col];
            // Logits bounded (|feat|max ~5.7, off <~4): exp w/o max-sub is fp32-safe.
            const float e = __expf(x + fmaxf(acc[t], 0.0f));
            ob[(size_t)i * NPTS] = e;
            float r = e;
            #pragma unroll
            for (int s = 32; s >= 1; s >>= 1) r += __shfl_xor(r, s, 64);
            if (col == 0) atomicAdd(&sums[b * K + i], r);   // 32 adds/row total
        }
    }
}

// One block per row: scale 2048 floats by 1/rowsum, float4 vectorized.
__global__ __launch_bounds__(256) void normalize_kernel(
    float* __restrict__ out, const float* __restrict__ sums)
{
    const size_t row = blockIdx.x;
    const float inv = 1.0f / sums[row];
    float4* p = reinterpret_cast<float4*>(out + row * NPTS);
    #pragma unroll
    for (int k = 0; k < NPTS / 1024; ++k) {         // 2 iterations
        float4 v = p[k * 256 + threadIdx.x];
        v.x *= inv; v.y *= inv; v.z *= inv; v.w *= inv;
        p[k * 256 + threadIdx.x] = v;
    }
}

extern "C" void kernel_launch(void* const* d_in, const int* in_sizes, int n_in,
                              void* d_out, int out_size, void* d_ws, size_t ws_size,
                              hipStream_t stream)
{
    const float* feat1 = (const float*)d_in[0];
    const float* feat2 = (const float*)d_in[1];
    const float* feat3 = (const float*)d_in[2];
    const float* cls   = (const float*)d_in[3];
    const float* W1    = (const float*)d_in[4];
    const float* b1    = (const float*)d_in[5];
    const float* W2    = (const float*)d_in[6];
    const float* b2    = (const float*)d_in[7];
    const float* W3    = (const float*)d_in[8];
    const float* b3    = (const float*)d_in[9];
    float* out = (float*)d_out;

    // ws layout: cid int[128] @0, rowsums float[28672] @512
    int*   cid  = (int*)d_ws;
    float* sums = (float*)((char*)d_ws + 512);
    const int nrows1 = B_SZ * 32, nrows2 = B_SZ * 64, nrows3 = B_SZ * 128;
    const int nsums  = nrows1 + nrows2 + nrows3;     // 28672

    prep_kernel<<<112, 256, 0, stream>>>(cls, cid, sums, nsums);

    float* out1 = out;
    float* out2 = out + (size_t)nrows1 * NPTS;
    float* out3 = out + (size_t)(nrows1 + nrows2) * NPTS;
    float* outc = out + (size_t)nsums * NPTS;

    expert_exp_kernel<32><<<B_SZ * 32, 256, 0, stream>>>(feat1, W1, b1, cid, out1, sums);
    expert_exp_kernel<64><<<B_SZ * 32, 256, 0, stream>>>(feat2, W2, b2, cid, out2, sums + nrows1);
    expert_exp_kernel<128><<<B_SZ * 32, 256, 0, stream>>>(feat3, W3, b3, cid, out3, sums + nrows1 + nrows2);

    normalize_kernel<<<nsums, 256, 0, stream>>>(out, sums);

    hipMemcpyAsync(outc, cls, (size_t)B_SZ * CATE * sizeof(float),
                   hipMemcpyDeviceToDevice, stream);
}

// Round 3
// 796.866 us; speedup vs baseline: 1.1873x; 1.1873x over previous
//
#include <hip/hip_runtime.h>

#define B_SZ 128
#define NPTS 2048
#define CATE 55

// prep: per-batch argmax of cls_score -> cid; zero the row-sum scratch.
__global__ __launch_bounds__(256) void prep_kernel(
    const float* __restrict__ cls, int* __restrict__ cid,
    float* __restrict__ sums, int nsums)
{
    int gt = blockIdx.x * 256 + threadIdx.x;
    if (gt < B_SZ) {
        const float* p = cls + gt * CATE;
        float best = p[0]; int bi = 0;
        #pragma unroll
        for (int i = 1; i < CATE; ++i) {
            float v = p[i];
            if (v > best) { best = v; bi = i; }   // strict > => first max, matches argmax
        }
        cid[gt] = bi;
    }
    for (int i = gt; i < nsums; i += gridDim.x * 256) sums[i] = 0.0f;
}

// ---------------------------------------------------------------------------
// Round-0 proven kernel (used for K=32, K=64 — LDS <= 16KB, 8 blocks/CU ok).
// Per j: 1 ds_read + 8 FMA (W wave-uniform -> s_load). 44 VGPR, no spill.
// Round-1's xr[32] register-tile regressed: compiler remat'd (VGPR stayed 44,
// VALU-issue tripled 88->266us). Do NOT reintroduce big unrolled reg arrays.
// ---------------------------------------------------------------------------
template<int K>
__global__ __launch_bounds__(256) void expert_exp_kernel(
    const float* __restrict__ feat,   // [B,K,NPTS]
    const float* __restrict__ W,      // [CATE,K,K]
    const float* __restrict__ bias,   // [CATE,K]
    const int*   __restrict__ cid,    // [B]
    float*       __restrict__ out,    // [B,K,NPTS] (exp values)
    float*       __restrict__ sums)   // [B*K]
{
    constexpr int RT = K / 4;                       // rows per thread
    const int b     = blockIdx.x >> 5;              // 2048/64 = 32 chunks
    const int chunk = blockIdx.x & 31;
    const int col   = threadIdx.x & 63;             // lane == column
    const int rg    = __builtin_amdgcn_readfirstlane(threadIdx.x >> 6); // wave id, SGPR
    const int c     = __builtin_amdgcn_readfirstlane(cid[b]);

    const float* Wc = W + (size_t)c * K * K;
    const float* bc = bias + (size_t)c * K;
    const float* fb = feat + (size_t)b * K * NPTS + chunk * 64;
    float*       ob = out  + (size_t)b * K * NPTS + chunk * 64 + col;

    __shared__ float xs[K * 64];                    // K=64 -> 16 KB

    // Stage feat tile: float4, 16 rows per 256-thread pass, coalesced.
    {
        const int r0 = threadIdx.x >> 4;            // 0..15
        const int c4 = (threadIdx.x & 15) << 2;     // 0,4,..,60
        #pragma unroll
        for (int p = 0; p < K / 16; ++p) {
            const int r = p * 16 + r0;
            const float4 v = *(const float4*)(fb + (size_t)r * NPTS + c4);
            *(float4*)(&xs[r * 64 + c4]) = v;
        }
    }
    __syncthreads();

    const int i0 = rg * RT;
    #pragma unroll 1
    for (int ic = 0; ic < RT; ic += 8) {
        float acc[8];
        #pragma unroll
        for (int t = 0; t < 8; ++t) acc[t] = bc[i0 + ic + t];

        #pragma unroll 4
        for (int j = 0; j < K; ++j) {
            const float xv = xs[j * 64 + col];      // stride-1: 2-way alias = free
            #pragma unroll
            for (int t = 0; t < 8; ++t)
                acc[t] = fmaf(Wc[(size_t)(i0 + ic + t) * K + j], xv, acc[t]);
        }

        #pragma unroll
        for (int t = 0; t < 8; ++t) {
            const int i = i0 + ic + t;
            const float x = xs[i * 64 + col];
            // Logits bounded (|feat|max ~5.7, off <~4): exp w/o max-sub is fp32-safe.
            const float e = __expf(x + fmaxf(acc[t], 0.0f));
            ob[(size_t)i * NPTS] = e;
            float r = e;
            #pragma unroll
            for (int s = 32; s >= 1; s >>= 1) r += __shfl_xor(r, s, 64);
            if (col == 0) atomicAdd(&sums[b * K + i], r);   // 32 adds/row total
        }
    }
}

// ---------------------------------------------------------------------------
// K=128 variant: j-dimension tiled (JT=64) so LDS drops 32KB -> 16KB, lifting
// blocks/CU from ~3.3 (41% occ) to the thread cap of 8 (8 waves/SIMD). The
// lgkmcnt(0) drains from mixed ds_read/s_load are unavoidable (shared counter,
// OOO completion) — more resident waves hide them. Same per-j instruction
// pattern as above. acc[RT=32] lives across both j-tiles (static indices via
// full unroll of the ic loop). Epilogue re-reads x from global (L3-resident).
// ---------------------------------------------------------------------------
template<int K, int JT>
__global__ __launch_bounds__(256) void expert_exp_tiled_kernel(
    const float* __restrict__ feat,   // [B,K,NPTS]
    const float* __restrict__ W,      // [CATE,K,K]
    const float* __restrict__ bias,   // [CATE,K]
    const int*   __restrict__ cid,    // [B]
    float*       __restrict__ out,    // [B,K,NPTS] (exp values)
    float*       __restrict__ sums)   // [B*K]
{
    constexpr int RT = K / 4;                       // rows per thread (32)
    const int b     = blockIdx.x >> 5;
    const int chunk = blockIdx.x & 31;
    const int col   = threadIdx.x & 63;
    const int rg    = __builtin_amdgcn_readfirstlane(threadIdx.x >> 6);
    const int c     = __builtin_amdgcn_readfirstlane(cid[b]);

    const float* Wc = W + (size_t)c * K * K;
    const float* bc = bias + (size_t)c * K;
    const float* fb = feat + (size_t)b * K * NPTS + chunk * 64;
    float*       ob = out  + (size_t)b * K * NPTS + chunk * 64 + col;

    __shared__ float xs[JT * 64];                   // 64x64 floats = 16 KB

    const int i0 = rg * RT;

    float acc[RT];
    #pragma unroll
    for (int i = 0; i < RT; ++i) acc[i] = bc[i0 + i];

    #pragma unroll
    for (int jt = 0; jt < K; jt += JT) {
        if (jt) __syncthreads();                    // previous tile fully consumed

        // Stage j-rows [jt, jt+JT) of the feat tile.
        {
            const int r0 = threadIdx.x >> 4;        // 0..15
            const int c4 = (threadIdx.x & 15) << 2; // 0,4,..,60
            #pragma unroll
            for (int p = 0; p < JT / 16; ++p) {
                const int r = p * 16 + r0;          // row within tile
                const float4 v = *(const float4*)(fb + (size_t)(jt + r) * NPTS + c4);
                *(float4*)(&xs[r * 64 + c4]) = v;
            }
        }
        __syncthreads();

        #pragma unroll
        for (int ic = 0; ic < RT; ic += 8) {        // full unroll -> static acc idx
            #pragma unroll 4
            for (int j = 0; j < JT; ++j) {
                const float xv = xs[j * 64 + col];
                #pragma unroll
                for (int t = 0; t < 8; ++t)
                    acc[ic + t] = fmaf(Wc[(size_t)(i0 + ic + t) * K + jt + j], xv, acc[ic + t]);
            }
        }
    }

    // Epilogue: x re-read from global (the 64-wide col chunk is a coalesced
    // 256B segment; feat3 = 134MB is L3-resident).
    #pragma unroll
    for (int i = 0; i < RT; ++i) {
        const float x = fb[(size_t)(i0 + i) * NPTS + col];
        const float e = __expf(x + fmaxf(acc[i], 0.0f));
        ob[(size_t)(i0 + i) * NPTS] = e;
        float r = e;
        #pragma unroll
        for (int s = 32; s >= 1; s >>= 1) r += __shfl_xor(r, s, 64);
        if (col == 0) atomicAdd(&sums[b * K + i0 + i], r);
    }
}

// One block per row: scale 2048 floats by 1/rowsum, float4 vectorized.
__global__ __launch_bounds__(256) void normalize_kernel(
    float* __restrict__ out, const float* __restrict__ sums)
{
    const size_t row = blockIdx.x;
    const float inv = 1.0f / sums[row];
    float4* p = reinterpret_cast<float4*>(out + row * NPTS);
    #pragma unroll
    for (int k = 0; k < NPTS / 1024; ++k) {         // 2 iterations
        float4 v = p[k * 256 + threadIdx.x];
        v.x *= inv; v.y *= inv; v.z *= inv; v.w *= inv;
        p[k * 256 + threadIdx.x] = v;
    }
}

extern "C" void kernel_launch(void* const* d_in, const int* in_sizes, int n_in,
                              void* d_out, int out_size, void* d_ws, size_t ws_size,
                              hipStream_t stream)
{
    const float* feat1 = (const float*)d_in[0];
    const float* feat2 = (const float*)d_in[1];
    const float* feat3 = (const float*)d_in[2];
    const float* cls   = (const float*)d_in[3];
    const float* W1    = (const float*)d_in[4];
    const float* b1    = (const float*)d_in[5];
    const float* W2    = (const float*)d_in[6];
    const float* b2    = (const float*)d_in[7];
    const float* W3    = (const float*)d_in[8];
    const float* b3    = (const float*)d_in[9];
    float* out = (float*)d_out;

    // ws layout: cid int[128] @0, rowsums float[28672] @512
    int*   cid  = (int*)d_ws;
    float* sums = (float*)((char*)d_ws + 512);
    const int nrows1 = B_SZ * 32, nrows2 = B_SZ * 64, nrows3 = B_SZ * 128;
    const int nsums  = nrows1 + nrows2 + nrows3;     // 28672

    prep_kernel<<<112, 256, 0, stream>>>(cls, cid, sums, nsums);

    float* out1 = out;
    float* out2 = out + (size_t)nrows1 * NPTS;
    float* out3 = out + (size_t)(nrows1 + nrows2) * NPTS;
    float* outc = out + (size_t)nsums * NPTS;

    expert_exp_kernel<32><<<B_SZ * 32, 256, 0, stream>>>(feat1, W1, b1, cid, out1, sums);
    expert_exp_kernel<64><<<B_SZ * 32, 256, 0, stream>>>(feat2, W2, b2, cid, out2, sums + nrows1);
    expert_exp_tiled_kernel<128, 64><<<B_SZ * 32, 256, 0, stream>>>(feat3, W3, b3, cid, out3, sums + nrows1 + nrows2);

    normalize_kernel<<<nsums, 256, 0, stream>>>(out, sums);

    hipMemcpyAsync(outc, cls, (size_t)B_SZ * CATE * sizeof(float),
                   hipMemcpyDeviceToDevice, stream);
}

// Round 4
// 761.688 us; speedup vs baseline: 1.2421x; 1.0462x over previous
//
#include <hip/hip_runtime.h>

#define B_SZ 128
#define NPTS 2048
#define CATE 55

// prep: per-batch argmax of cls_score -> cid; zero the row-sum scratch.
__global__ __launch_bounds__(256) void prep_kernel(
    const float* __restrict__ cls, int* __restrict__ cid,
    float* __restrict__ sums, int nsums)
{
    int gt = blockIdx.x * 256 + threadIdx.x;
    if (gt < B_SZ) {
        const float* p = cls + gt * CATE;
        float best = p[0]; int bi = 0;
        #pragma unroll
        for (int i = 1; i < CATE; ++i) {
            float v = p[i];
            if (v > best) { best = v; bi = i; }   // strict > => first max, matches argmax
        }
        cid[gt] = bi;
    }
    for (int i = gt; i < nsums; i += gridDim.x * 256) sums[i] = 0.0f;
}

// ---------------------------------------------------------------------------
// Round-4: W via LDS instead of s_load.
// Evidence: occupancy 41->68% (r3) changed NOTHING (dur 309->304, VALUBusy
// ~29% both) -> stall is a saturated shared per-CU resource, not latency.
// The only shared resource the loop hammers is the SMEM unit (8 s_load_dwordx4
// of W per j-group; shallow queue to L2 caps ~0.16 req/cy -> 29% VALU cap,
// occupancy-independent). r1 cross-check: 3x more VALU per SMEM byte -> 63%.
// Fix: stage W TRANSPOSED in LDS (wst[j][row^swz]); inner loop reads W as
// 2 wave-uniform ds_read_b128 (broadcast, conflict-free) per j. All inner
// memory on lgkmcnt -> compiler emits counted waits; SMEM idle.
// Swizzle swz(j) = ((j>>2)&3)<<3: bits>=3 only -> 8-row b128 contiguity kept;
// staging write conflicts 16-way -> 4-way.
// ---------------------------------------------------------------------------
template<int K, int JT>
__global__ __launch_bounds__(256) void expert_exp_ldsw_kernel(
    const float* __restrict__ feat,   // [B,K,NPTS]
    const float* __restrict__ W,      // [CATE,K,K]
    const float* __restrict__ bias,   // [CATE,K]
    const int*   __restrict__ cid,    // [B]
    float*       __restrict__ out,    // [B,K,NPTS] (exp values)
    float*       __restrict__ sums)   // [B*K]
{
    constexpr int RT  = K / 4;                      // rows per thread
    constexpr int JG  = JT / 4;                     // float4 groups along j
    constexpr int RPP = 256 / JG;                   // W-staging rows per pass
    const int b     = blockIdx.x >> 5;              // 2048/64 = 32 chunks
    const int chunk = blockIdx.x & 31;
    const int col   = threadIdx.x & 63;             // lane == column
    const int rg    = __builtin_amdgcn_readfirstlane(threadIdx.x >> 6);
    const int c     = __builtin_amdgcn_readfirstlane(cid[b]);

    const float* Wc = W + (size_t)c * K * K;
    const float* bc = bias + (size_t)c * K;
    const float* fb = feat + (size_t)b * K * NPTS + chunk * 64;
    float*       ob = out  + (size_t)b * K * NPTS + chunk * 64 + col;

    __shared__ __align__(16) float xs[JT * 64];     // x tile   [j][col]
    __shared__ __align__(16) float wst[JT * K];     // W tile   [j][row ^ swz(j)]

    const int i0 = rg * RT;

    float acc[RT];
    #pragma unroll
    for (int i = 0; i < RT; ++i) acc[i] = bc[i0 + i];

    #pragma unroll
    for (int jt = 0; jt < K; jt += JT) {
        if (jt) __syncthreads();                    // previous tile consumed

        // Stage x rows [jt, jt+JT): float4, coalesced, conflict-free (proven).
        {
            const int r0 = threadIdx.x >> 4;        // 0..15
            const int c4 = (threadIdx.x & 15) << 2; // 0,4,..,60
            #pragma unroll
            for (int p = 0; p < JT / 16; ++p) {
                const int r = p * 16 + r0;
                *(float4*)(&xs[r * 64 + c4]) =
                    *(const float4*)(fb + (size_t)(jt + r) * NPTS + c4);
            }
        }
        // Stage W cols [jt, jt+JT) x all K rows, transposed + swizzled.
        // Global read: consecutive tids -> consecutive cols in a row (coalesced).
        // LDS write: 4 scalar stores; banks = (row^swz)%32 -> 16 banks = 4-way.
        {
            const int jc4 = threadIdx.x % JG;       // float4 index along j
            const int rr  = threadIdx.x / JG;       // row offset within pass
            const int swz = (jc4 & 3) << 3;
            #pragma unroll
            for (int p = 0; p < K / RPP; ++p) {
                const int row = p * RPP + rr;
                const float4 wv = *(const float4*)(Wc + (size_t)row * K + jt + 4 * jc4);
                const int rs = row ^ swz;
                wst[(4 * jc4 + 0) * K + rs] = wv.x;
                wst[(4 * jc4 + 1) * K + rs] = wv.y;
                wst[(4 * jc4 + 2) * K + rs] = wv.z;
                wst[(4 * jc4 + 3) * K + rs] = wv.w;
            }
        }
        __syncthreads();

        // Inner loop: per j = 1 per-lane ds_read_b32 (x) + 2 uniform
        // ds_read_b128 (W rows i0+ic..+7, broadcast) + 8 FMA. All lgkmcnt.
        #pragma unroll
        for (int ic = 0; ic < RT; ic += 8) {        // static acc indices
            #pragma unroll 4
            for (int j = 0; j < JT; ++j) {
                const float xv = xs[j * 64 + col];
                const int rbase = (i0 + ic) ^ (((j >> 2) & 3) << 3);
                const float4 w0 = *(const float4*)(&wst[j * K + rbase]);
                const float4 w1 = *(const float4*)(&wst[j * K + rbase + 4]);
                acc[ic + 0] = fmaf(w0.x, xv, acc[ic + 0]);
                acc[ic + 1] = fmaf(w0.y, xv, acc[ic + 1]);
                acc[ic + 2] = fmaf(w0.z, xv, acc[ic + 2]);
                acc[ic + 3] = fmaf(w0.w, xv, acc[ic + 3]);
                acc[ic + 4] = fmaf(w1.x, xv, acc[ic + 4]);
                acc[ic + 5] = fmaf(w1.y, xv, acc[ic + 5]);
                acc[ic + 6] = fmaf(w1.z, xv, acc[ic + 6]);
                acc[ic + 7] = fmaf(w1.w, xv, acc[ic + 7]);
            }
        }
    }

    // Epilogue: x re-read from global (coalesced 256B segments, L2-resident).
    #pragma unroll
    for (int i = 0; i < RT; ++i) {
        const float x = fb[(size_t)(i0 + i) * NPTS + col];
        const float e = __expf(x + fmaxf(acc[i], 0.0f));
        ob[(size_t)(i0 + i) * NPTS] = e;
        float r = e;
        #pragma unroll
        for (int s = 32; s >= 1; s >>= 1) r += __shfl_xor(r, s, 64);
        if (col == 0) atomicAdd(&sums[b * K + i0 + i], r);
    }
}

// One block per row: scale 2048 floats by 1/rowsum, float4 vectorized.
__global__ __launch_bounds__(256) void normalize_kernel(
    float* __restrict__ out, const float* __restrict__ sums)
{
    const size_t row = blockIdx.x;
    const float inv = 1.0f / sums[row];
    float4* p = reinterpret_cast<float4*>(out + row * NPTS);
    #pragma unroll
    for (int k = 0; k < NPTS / 1024; ++k) {         // 2 iterations
        float4 v = p[k * 256 + threadIdx.x];
        v.x *= inv; v.y *= inv; v.z *= inv; v.w *= inv;
        p[k * 256 + threadIdx.x] = v;
    }
}

extern "C" void kernel_launch(void* const* d_in, const int* in_sizes, int n_in,
                              void* d_out, int out_size, void* d_ws, size_t ws_size,
                              hipStream_t stream)
{
    const float* feat1 = (const float*)d_in[0];
    const float* feat2 = (const float*)d_in[1];
    const float* feat3 = (const float*)d_in[2];
    const float* cls   = (const float*)d_in[3];
    const float* W1    = (const float*)d_in[4];
    const float* b1    = (const float*)d_in[5];
    const float* W2    = (const float*)d_in[6];
    const float* b2    = (const float*)d_in[7];
    const float* W3    = (const float*)d_in[8];
    const float* b3    = (const float*)d_in[9];
    float* out = (float*)d_out;

    // ws layout: cid int[128] @0, rowsums float[28672] @512
    int*   cid  = (int*)d_ws;
    float* sums = (float*)((char*)d_ws + 512);
    const int nrows1 = B_SZ * 32, nrows2 = B_SZ * 64, nrows3 = B_SZ * 128;
    const int nsums  = nrows1 + nrows2 + nrows3;     // 28672

    prep_kernel<<<112, 256, 0, stream>>>(cls, cid, sums, nsums);

    float* out1 = out;
    float* out2 = out + (size_t)nrows1 * NPTS;
    float* out3 = out + (size_t)(nrows1 + nrows2) * NPTS;
    float* outc = out + (size_t)nsums * NPTS;

    // LDS: K=32 -> 12KB, K=64 -> 32KB, K=128 -> 48KB (3 blocks/CU).
    expert_exp_ldsw_kernel<32, 32><<<B_SZ * 32, 256, 0, stream>>>(feat1, W1, b1, cid, out1, sums);
    expert_exp_ldsw_kernel<64, 64><<<B_SZ * 32, 256, 0, stream>>>(feat2, W2, b2, cid, out2, sums + nrows1);
    expert_exp_ldsw_kernel<128, 64><<<B_SZ * 32, 256, 0, stream>>>(feat3, W3, b3, cid, out3, sums + nrows1 + nrows2);

    normalize_kernel<<<nsums, 256, 0, stream>>>(out, sums);

    hipMemcpyAsync(outc, cls, (size_t)B_SZ * CATE * sizeof(float),
                   hipMemcpyDeviceToDevice, stream);
}

// Round 5
// 592.456 us; speedup vs baseline: 1.5969x; 1.2856x over previous
//
#include <hip/hip_runtime.h>

#define B_SZ 128
#define NPTS 2048
#define CATE 55

// prep: per-batch argmax of cls_score -> cid; zero the row-sum scratch.
__global__ __launch_bounds__(256) void prep_kernel(
    const float* __restrict__ cls, int* __restrict__ cid,
    float* __restrict__ sums, int nsums)
{
    int gt = blockIdx.x * 256 + threadIdx.x;
    if (gt < B_SZ) {
        const float* p = cls + gt * CATE;
        float best = p[0]; int bi = 0;
        #pragma unroll
        for (int i = 1; i < CATE; ++i) {
            float v = p[i];
            if (v > best) { best = v; bi = i; }   // strict > => first max, matches argmax
        }
        cid[gt] = bi;
    }
    for (int i = gt; i < nsums; i += gridDim.x * 256) sums[i] = 0.0f;
}

// ---------------------------------------------------------------------------
// v5: 2D register tile (RPT rows x 4 cols per thread).
// Evidence chain: r3 (occupancy 41->68%) = no effect; r4 (W off SMEM onto
// LDS) = 304->284 only, VALUBusy 35%. Cap = LDS-instr issue: old loop was
// 3 LDS instrs / 8 FMA; LDS unit is per-CU shared by 4 SIMDs -> VALU cap
// ~33% (measured 35%). This version: 3 LDS instrs / 32 FMA (K=128) by
// giving each thread 4 columns (float4 x-read) and RPT rows.
// Lane map: cg = tid&15 (cols 4cg..+3), rg = tid>>4 (rows RPT*rg..).
//  x read  xs[j][4cg]      : 16 distinct b128/wave -> 2-way = free.
//  W read  wst[j][RPT*rg]  : 4 distinct b128/wave, quads {0,8,16,24} -> free,
//                            broadcast within 16-lane groups.
//  W stage: coalesced global float4, scalar LDS writes 8-way conflicted
//           (bounded ~10us by r4's 6.3M-cycle measurement; accepted).
// Only acc[RPT][4] persists; static indices everywhere (r1 remat trap).
// ---------------------------------------------------------------------------
template<int K, int RPT>
__global__ __launch_bounds__(256) void expert_v5_kernel(
    const float* __restrict__ feat,   // [B,K,NPTS]
    const float* __restrict__ W,      // [CATE,K,K]
    const float* __restrict__ bias,   // [CATE,K]
    const int*   __restrict__ cid,    // [B]
    float*       __restrict__ out,    // [B,K,NPTS] (exp values)
    float*       __restrict__ sums)   // [B*K]
{
    constexpr int JT = 32;                          // j-tile
    const int b     = blockIdx.x >> 5;              // 2048/64 = 32 chunks
    const int chunk = blockIdx.x & 31;
    const int tid   = threadIdx.x;
    const int cg    = tid & 15;                     // col-group
    const int rg    = tid >> 4;                     // row-group (0..15)
    const int c     = __builtin_amdgcn_readfirstlane(cid[b]);

    const float* Wc = W + (size_t)c * K * K;
    const float* bc = bias + (size_t)c * K;
    const float* fb = feat + (size_t)b * K * NPTS + chunk * 64;
    float*       ob = out  + (size_t)b * K * NPTS + chunk * 64;

    __shared__ __align__(16) float xs[JT * 64];     // x tile [j][col]
    __shared__ __align__(16) float wst[JT * K];     // W tile [j][row]

    const int r0 = rg * RPT;

    float acc[RPT][4];
    #pragma unroll
    for (int r = 0; r < RPT; ++r) {
        const float bv = bc[r0 + r];
        #pragma unroll
        for (int u = 0; u < 4; ++u) acc[r][u] = bv;
    }

    #pragma unroll 1
    for (int jt = 0; jt < K; jt += JT) {
        if (jt) __syncthreads();                    // previous tile consumed

        // Stage x rows [jt, jt+JT): float4, coalesced, conflict-free.
        {
            const int xr = tid >> 4;                // 0..15
            const int xc = (tid & 15) << 2;         // 0,4,..,60
            #pragma unroll
            for (int p = 0; p < JT / 16; ++p) {
                *(float4*)(&xs[(p * 16 + xr) * 64 + xc]) =
                    *(const float4*)(fb + (size_t)(jt + p * 16 + xr) * NPTS + xc);
            }
        }
        // Stage W transposed: thread (row, jc4) loads Wc[row][jt+4jc4..+3]
        // (coalesced: 8 consecutive float4 per row-octet), writes 4 scalars
        // wst[4jc4+u][row]. Write banks = row%32 shared by 8 lanes -> 8-way
        // (staging-only, accepted). Read side conflict-free.
        {
            const int jc4 = tid & 7;                // 0..7
            const int wr0 = tid >> 3;               // 0..31
            #pragma unroll
            for (int p = 0; p < K / 32; ++p) {
                const int row = p * 32 + wr0;
                const float4 wv = *(const float4*)(Wc + (size_t)row * K + jt + 4 * jc4);
                wst[(4 * jc4 + 0) * K + row] = wv.x;
                wst[(4 * jc4 + 1) * K + row] = wv.y;
                wst[(4 * jc4 + 2) * K + row] = wv.z;
                wst[(4 * jc4 + 3) * K + row] = wv.w;
            }
        }
        __syncthreads();

        // Inner: per j = 1 b128 x (per-lane) + RPT/4 b128 W (broadcast)
        // + 4*RPT FMAs, all static acc indices.
        #pragma unroll 2
        for (int jl = 0; jl < JT; ++jl) {
            const float4 xv = *(const float4*)(&xs[jl * 64 + 4 * cg]);
            float xa[4] = {xv.x, xv.y, xv.z, xv.w};
            float wr[RPT];
            if constexpr (RPT == 8) {
                const float4 w0 = *(const float4*)(&wst[jl * K + r0]);
                const float4 w1 = *(const float4*)(&wst[jl * K + r0 + 4]);
                wr[0] = w0.x; wr[1] = w0.y; wr[2] = w0.z; wr[3] = w0.w;
                wr[4] = w1.x; wr[5] = w1.y; wr[6] = w1.z; wr[7] = w1.w;
            } else if constexpr (RPT == 4) {
                const float4 w0 = *(const float4*)(&wst[jl * K + r0]);
                wr[0] = w0.x; wr[1] = w0.y; wr[2] = w0.z; wr[3] = w0.w;
            } else {
                const float2 w0 = *(const float2*)(&wst[jl * K + r0]);
                wr[0] = w0.x; wr[1] = w0.y;
            }
            #pragma unroll
            for (int r = 0; r < RPT; ++r)
                #pragma unroll
                for (int u = 0; u < 4; ++u)
                    acc[r][u] = fmaf(wr[r], xa[u], acc[r][u]);
        }
    }

    // Epilogue: x re-read from global (coalesced float4, L2/L3-hot).
    #pragma unroll
    for (int r = 0; r < RPT; ++r) {
        const int row = r0 + r;
        const float4 xv = *(const float4*)(fb + (size_t)row * NPTS + 4 * cg);
        float4 e;
        // Logits bounded (|feat|max ~5.7, off <~4): exp w/o max-sub is fp32-safe.
        e.x = __expf(xv.x + fmaxf(acc[r][0], 0.0f));
        e.y = __expf(xv.y + fmaxf(acc[r][1], 0.0f));
        e.z = __expf(xv.z + fmaxf(acc[r][2], 0.0f));
        e.w = __expf(xv.w + fmaxf(acc[r][3], 0.0f));
        *(float4*)(ob + (size_t)row * NPTS + 4 * cg) = e;
        float rs = e.x + e.y + e.z + e.w;
        #pragma unroll
        for (int s = 8; s >= 1; s >>= 1) rs += __shfl_xor(rs, s, 64);
        if (cg == 0) atomicAdd(&sums[b * K + row], rs);   // 32 adds/row total
    }
}

// One block per row: scale 2048 floats by 1/rowsum, float4 vectorized.
__global__ __launch_bounds__(256) void normalize_kernel(
    float* __restrict__ out, const float* __restrict__ sums)
{
    const size_t row = blockIdx.x;
    const float inv = 1.0f / sums[row];
    float4* p = reinterpret_cast<float4*>(out + row * NPTS);
    #pragma unroll
    for (int k = 0; k < NPTS / 1024; ++k) {         // 2 iterations
        float4 v = p[k * 256 + threadIdx.x];
        v.x *= inv; v.y *= inv; v.z *= inv; v.w *= inv;
        p[k * 256 + threadIdx.x] = v;
    }
}

extern "C" void kernel_launch(void* const* d_in, const int* in_sizes, int n_in,
                              void* d_out, int out_size, void* d_ws, size_t ws_size,
                              hipStream_t stream)
{
    const float* feat1 = (const float*)d_in[0];
    const float* feat2 = (const float*)d_in[1];
    const float* feat3 = (const float*)d_in[2];
    const float* cls   = (const float*)d_in[3];
    const float* W1    = (const float*)d_in[4];
    const float* b1    = (const float*)d_in[5];
    const float* W2    = (const float*)d_in[6];
    const float* b2    = (const float*)d_in[7];
    const float* W3    = (const float*)d_in[8];
    const float* b3    = (const float*)d_in[9];
    float* out = (float*)d_out;

    // ws layout: cid int[128] @0, rowsums float[28672] @512
    int*   cid  = (int*)d_ws;
    float* sums = (float*)((char*)d_ws + 512);
    const int nrows1 = B_SZ * 32, nrows2 = B_SZ * 64, nrows3 = B_SZ * 128;
    const int nsums  = nrows1 + nrows2 + nrows3;     // 28672

    prep_kernel<<<112, 256, 0, stream>>>(cls, cid, sums, nsums);

    float* out1 = out;
    float* out2 = out + (size_t)nrows1 * NPTS;
    float* out3 = out + (size_t)(nrows1 + nrows2) * NPTS;
    float* outc = out + (size_t)nsums * NPTS;

    // LDS: K=32 -> 12KB, K=64 -> 16KB, K=128 -> 24KB (6 blocks/CU).
    expert_v5_kernel<32, 2><<<B_SZ * 32, 256, 0, stream>>>(feat1, W1, b1, cid, out1, sums);
    expert_v5_kernel<64, 4><<<B_SZ * 32, 256, 0, stream>>>(feat2, W2, b2, cid, out2, sums + nrows1);
    expert_v5_kernel<128, 8><<<B_SZ * 32, 256, 0, stream>>>(feat3, W3, b3, cid, out3, sums + nrows1 + nrows2);

    normalize_kernel<<<nsums, 256, 0, stream>>>(out, sums);

    hipMemcpyAsync(outc, cls, (size_t)B_SZ * CATE * sizeof(float),
                   hipMemcpyDeviceToDevice, stream);
}